// Round 6
// baseline (609.856 us; speedup 1.0000x reference)
//
#include <hip/hip_runtime.h>

#define NB 4
#define NS 512
#define NC 128
#define NV 128

typedef _Float16 half8 __attribute__((ext_vector_type(8)));
typedef float f32x4 __attribute__((ext_vector_type(4)));

__device__ __forceinline__ float fast_tanh(float x) {
  float e = __expf(2.0f * x);
  return 1.0f - __fdividef(2.0f, e + 1.0f);
}

// ---------------- prep kernel ----------------
// Gp[b,i,v]  = ctx[b,i]·(W2-Wd)[v] + (b1+b2+bm+bd)[v]   (all i-only + const terms)
// WmH[v,c]   = fp16(Wm[v,c])
// WHdH[v,c]  = fp16(W1[v,c] + Wd[v,c])                  (j-side weight fold)
// ctx_h      = fp16(ctx)
// grid: NB*NS/8 = 256 blocks, 128 threads
__global__ __launch_bounds__(128) void prep_kernel(
    const float* __restrict__ ctx,
    const float* __restrict__ W1, const float* __restrict__ b1,
    const float* __restrict__ W2, const float* __restrict__ b2,
    const float* __restrict__ Wm,
    const float* __restrict__ bm,
    const float* __restrict__ Wd, const float* __restrict__ bd,
    _Float16* __restrict__ ctx_h,
    float* __restrict__ Gp,
    _Float16* __restrict__ WmH,
    _Float16* __restrict__ WHdH)
{
  __shared__ float xr[8][NC];
  const int row0 = blockIdx.x * 8;
  const int t = threadIdx.x;

  // fp16 weight copies, sliced across the 256 blocks (64 entries each)
  {
    const int base = blockIdx.x * 64;
    if (t < 64) {
      WmH[base + t]  = (_Float16)Wm[base + t];
      WHdH[base + t] = (_Float16)(W1[base + t] + Wd[base + t]);
    }
  }

  #pragma unroll
  for (int rr = 0; rr < 8; ++rr) {
    float x = ctx[(size_t)(row0 + rr) * NC + t];
    xr[rr][t] = x;
    ctx_h[(size_t)(row0 + rr) * NC + t] = (_Float16)x;
  }
  __syncthreads();

  const int v = t;
  float acc[8];
  const float bG = b1[v] + b2[v] + bm[v] + bd[v];
  #pragma unroll
  for (int rr = 0; rr < 8; ++rr) acc[rr] = bG;

  for (int c4 = 0; c4 < NC; c4 += 4) {
    f32x4 w2 = *(const f32x4*)(W2 + v * NC + c4);
    f32x4 wd = *(const f32x4*)(Wd + v * NC + c4);
    #pragma unroll
    for (int u = 0; u < 4; ++u) {
      const float wG = w2[u] - wd[u];
      const int c = c4 + u;
      #pragma unroll
      for (int rr = 0; rr < 8; ++rr) acc[rr] = fmaf(xr[rr][c], wG, acc[rr]);
    }
  }
  #pragma unroll
  for (int rr = 0; rr < 8; ++rr) Gp[(size_t)(row0 + rr) * NV + v] = acc[rr];
}

// ---------------- main kernel ----------------
// One block per (b,i). NO LDS, NO BARRIERS — pure streaming.
// out[b,i,j,v] = tanh( ctx_j · Bm'[v] + Gp[b,i,v] ),
//   Bm'[v,c] = WmH[v,c]*xi_h[c] + WHdH[v,c]   (built per-lane in registers, fp16 pk-fma)
// MFMA 16x16x32_f16, Bm' as A-operand (M=v), ctx_j as B-operand (N=j):
// D lane layout: col=l&15 -> j-offset, row=(l>>4)*4+reg -> v-offset => float4 stores.
__global__ __launch_bounds__(256, 2) void main_kernel(
    const _Float16* __restrict__ WmH,
    const _Float16* __restrict__ WHdH,
    const _Float16* __restrict__ ctx_h,
    const float* __restrict__ Gp,
    float* __restrict__ out)
{
  const int bx = blockIdx.x;
  const int b = bx >> 9;          // NS = 512
  const int i = bx & (NS - 1);
  const int tid = threadIdx.x;
  const int w = tid >> 6;
  const int l = tid & 63;
  const int r = l & 15;
  const int q = l >> 4;

  // per-lane xi chunks: xq[ks] = xi_h[ks*32 + q*8 .. +7]
  const _Float16* xi = ctx_h + (size_t)(b * NS + i) * NC;
  half8 xq[4];
  #pragma unroll
  for (int ks = 0; ks < 4; ++ks) xq[ks] = *(const half8*)(xi + ks * 32 + q * 8);

  // B' fragments straight from global (L2-resident), no LDS:
  // lane needs WmH/WHdH row v=n*16+r, halfs [ks*32+q*8 .. +7] (16B aligned)
  half8 Bf[8][4];
  #pragma unroll
  for (int n = 0; n < 8; ++n) {
    const size_t rowoff = (size_t)(n * 16 + r) * NC + q * 8;
    #pragma unroll
    for (int ks = 0; ks < 4; ++ks) {
      half8 wm = *(const half8*)(WmH + rowoff + ks * 32);
      half8 wh = *(const half8*)(WHdH + rowoff + ks * 32);
      Bf[n][ks] = wm * xq[ks] + wh;   // v_pk_fma_f16
    }
  }

  // Per-lane accumulator init vector: Gp[b,i, n*16 + q*4 + reg] (float4)
  f32x4 Gv[8];
  const float* gp = Gp + (size_t)(b * NS + i) * NV;
  #pragma unroll
  for (int n = 0; n < 8; ++n) Gv[n] = *(const f32x4*)(gp + n * 16 + q * 4);

  const _Float16* ah_base = ctx_h + (size_t)(b * NS) * NC;
  float* out_base = out + ((size_t)(b * NS + i) * NS) * NV;

  for (int tt = 0; tt < 8; ++tt) {
    const int j0 = tt * 64 + w * 16;

    // ctx_j fragments (B-operand): col=l&15 -> j, k=(l>>4)*8+e
    half8 A[4];
    const _Float16* ap = ah_base + (size_t)(j0 + r) * NC + q * 8;
    #pragma unroll
    for (int ks = 0; ks < 4; ++ks) A[ks] = *(const half8*)(ap + ks * 32);

    f32x4 acc[8];
    #pragma unroll
    for (int n = 0; n < 8; ++n) acc[n] = Gv[n];   // fold i-side affine into C-init

    #pragma unroll
    for (int ks = 0; ks < 4; ++ks) {
      #pragma unroll
      for (int n = 0; n < 8; ++n) {
        acc[n] = __builtin_amdgcn_mfma_f32_16x16x32_f16(Bf[n][ks], A[ks], acc[n], 0, 0, 0);
      }
    }

    // Epilogue: lane writes out[b,i, j0+r, n*16 + q*4 .. +3] as float4
    float* op = out_base + (size_t)(j0 + r) * NV + q * 4;
    #pragma unroll
    for (int n = 0; n < 8; ++n) {
      f32x4 o;
      #pragma unroll
      for (int rr = 0; rr < 4; ++rr) o[rr] = fast_tanh(acc[n][rr]);
      *(f32x4*)(op + n * 16) = o;
    }
  }
}

extern "C" void kernel_launch(void* const* d_in, const int* in_sizes, int n_in,
                              void* d_out, int out_size, void* d_ws, size_t ws_size,
                              hipStream_t stream) {
  const float* ctx = (const float*)d_in[0];
  const float* W1  = (const float*)d_in[1];
  const float* b1  = (const float*)d_in[2];
  const float* W2  = (const float*)d_in[3];
  const float* b2  = (const float*)d_in[4];
  const float* Wm  = (const float*)d_in[5];
  const float* bm  = (const float*)d_in[6];
  const float* Wd  = (const float*)d_in[7];
  const float* bd  = (const float*)d_in[8];
  float* out = (float*)d_out;

  char* ws = (char*)d_ws;
  _Float16* ctx_h = (_Float16*)ws;                                     // 512 KB
  float* Gp = (float*)(ws + (size_t)NB * NS * NC * sizeof(_Float16));  // 1 MB
  _Float16* WmH  = (_Float16*)(Gp + (size_t)NB * NS * NV);             // 32 KB
  _Float16* WHdH = WmH + (size_t)NV * NC;                              // 32 KB

  prep_kernel<<<NB * NS / 8, 128, 0, stream>>>(ctx, W1, b1, W2, b2, Wm, bm, Wd, bd,
                                               ctx_h, Gp, WmH, WHdH);
  main_kernel<<<NB * NS, 256, 0, stream>>>(WmH, WHdH, ctx_h, Gp, out);
}